// Round 5
// baseline (906.960 us; speedup 1.0000x reference)
//
#include <hip/hip_runtime.h>
#include <stdint.h>

#define D 128
#define BETA 0.40546510810816444f   // log(1.5)
#define TSTR 136                     // padded LDS row stride (bf16 elems)

typedef __bf16 bf16x8 __attribute__((ext_vector_type(8)));
typedef float f32x4 __attribute__((ext_vector_type(4)));

__device__ __forceinline__ float bf2f(uint16_t u) {
    union { uint32_t i; float f; } x; x.i = ((uint32_t)u) << 16; return x.f;
}
__device__ __forceinline__ uint16_t f2bf(float f) {
    union { float f; uint32_t i; } x; x.f = f;
    uint32_t r = (x.i + 0x7fffu + ((x.i >> 16) & 1u)) >> 16;
    return (uint16_t)r;
}
__device__ __forceinline__ float lo_f(uint32_t u) { return __uint_as_float(u << 16); }
__device__ __forceinline__ float hi_f(uint32_t u) { return __uint_as_float(u & 0xffff0000u); }
__device__ __forceinline__ uint32_t pack2(float x, float y) {
    return (uint32_t)f2bf(x) | ((uint32_t)f2bf(y) << 16);
}

// ================= CSR build =================
__global__ void k_hist(const int* __restrict__ row, int* __restrict__ deg, int E, int N) {
    int e = blockIdx.x * blockDim.x + threadIdx.x;
    if (e < E) {
        int r = row[e]; r = min(max(r, 0), N - 1);
        atomicAdd(&deg[r], 1);
    }
}

__global__ void k_scan1(const int* __restrict__ deg, int* __restrict__ inc,
                        int* __restrict__ bsum, int n) {
    __shared__ int s[1024];
    int i = blockIdx.x * 1024 + threadIdx.x;
    int v = (i < n) ? deg[i] : 0;
    s[threadIdx.x] = v;
    __syncthreads();
    for (int d = 1; d < 1024; d <<= 1) {
        int t = (threadIdx.x >= (unsigned)d) ? s[threadIdx.x - d] : 0;
        __syncthreads();
        s[threadIdx.x] += t;
        __syncthreads();
    }
    if (i < n) inc[i] = s[threadIdx.x];
    if (threadIdx.x == 1023) bsum[blockIdx.x] = s[1023];
}

__global__ void k_scan2(const int* __restrict__ bsum, int* __restrict__ boff,
                        int nb, int* __restrict__ rowptr, int N) {
    int run = 0;
    for (int b = 0; b < nb; b++) { boff[b] = run; run += bsum[b]; }
    rowptr[N] = run;
}

__global__ void k_scan3(const int* __restrict__ deg, const int* __restrict__ boff,
                        int* __restrict__ rowptr, int* __restrict__ wp, int n) {
    int i = blockIdx.x * 1024 + threadIdx.x;
    if (i < n) {
        int ex = rowptr[i] - deg[i] + boff[blockIdx.x];
        rowptr[i] = ex;
        wp[i] = ex;
    }
}

__global__ void k_scatter(const int* __restrict__ row, const int* __restrict__ col,
                          const float* __restrict__ vals, int* __restrict__ wp,
                          int* __restrict__ ccol, uint16_t* __restrict__ cvalb,
                          int E, int N) {
    int e = blockIdx.x * blockDim.x + threadIdx.x;
    if (e < E) {
        int r = row[e]; r = min(max(r, 0), N - 1);
        int pos = atomicAdd(&wp[r], 1);
        pos = min(max(pos, 0), E - 1);
        ccol[pos] = col[e];
        cvalb[pos] = f2bf(vals[e]);
    }
}

// ======== ego f32 -> packed bf16 dwords (halves gather traffic) ========
__global__ void k_cvt(const float2* __restrict__ src, uint32_t* __restrict__ dst, int n) {
    int i = blockIdx.x * blockDim.x + threadIdx.x;
    if (i < n) { float2 v = src[i]; dst[i] = pack2(v.x, v.y); }
}

// ======== M1T=(IM@w1)^T, M2T=(IM@w2)^T, n-major, bf16 ========
__global__ void k_prep(const float* __restrict__ W, const float* __restrict__ w1,
                       const float* __restrict__ w2, uint16_t* __restrict__ M1T,
                       uint16_t* __restrict__ M2T) {
    int k = blockIdx.x, n = threadIdx.x;
    __shared__ float imrow[D];
    imrow[n] = (1.0f - BETA) + BETA * W[k * D + n];
    __syncthreads();
    float s1 = 0.f, s2 = 0.f;
    for (int j = 0; j < D; j++) {
        float im = imrow[j];
        s1 += im * w1[j * D + n];
        s2 += im * w2[j * D + n];
    }
    M1T[n * D + k] = f2bf(s1);
    M2T[n * D + k] = f2bf(s2);
}

// ======== shared phase-2: dual MFMA GEMM + leaky-relu epilogue (f32 out) ====
// A frag: A[m=lane&15][k=quad*8+j] (LDS, stride TSTR). B frag from n-major M*T.
// C/D: col=lane&15, row=quad*4+reg (m89-verified).
__device__ __forceinline__ void gemm_phase(
        const uint16_t* sT1, const uint16_t* sT2,
        const uint16_t* __restrict__ M1T, const uint16_t* __restrict__ M2T,
        const float* __restrict__ b1, const float* __restrict__ b2,
        float* __restrict__ out, int base, int wave, int lane, int N) {
    int l15 = lane & 15, quad = lane >> 4;
#pragma unroll
    for (int t = 0; t < 2; t++) {
        int tn = wave * 2 + t;
        f32x4 acc1 = {0.f, 0.f, 0.f, 0.f}, acc2 = {0.f, 0.f, 0.f, 0.f};
#pragma unroll
        for (int kb = 0; kb < 4; kb++) {
            int ko = kb * 32 + quad * 8;
            bf16x8 a1 = *(const bf16x8*)(sT1 + l15 * TSTR + ko);
            bf16x8 a2 = *(const bf16x8*)(sT2 + l15 * TSTR + ko);
            bf16x8 bb1 = *(const bf16x8*)(M1T + (tn * 16 + l15) * D + ko);
            bf16x8 bb2 = *(const bf16x8*)(M2T + (tn * 16 + l15) * D + ko);
            acc1 = __builtin_amdgcn_mfma_f32_16x16x32_bf16(a1, bb1, acc1, 0, 0, 0);
            acc2 = __builtin_amdgcn_mfma_f32_16x16x32_bf16(a2, bb2, acc2, 0, 0, 0);
        }
        int colo = tn * 16 + l15;
        float bbias1 = b1[colo], bbias2 = b2[colo];
#pragma unroll
        for (int r = 0; r < 4; r++) {
            int rowi = base + quad * 4 + r;
            if (rowi < N) {
                float v1 = acc1[r] + bbias1;
                v1 = (v1 >= 0.f) ? v1 : 0.01f * v1;
                float v2 = acc2[r] + bbias2;
                v2 = (v2 >= 0.f) ? v2 : 0.01f * v2;
                out[(size_t)rowi * D + colo] = v1 + v2;   // FLOAT32 output
            }
        }
    }
}

// ======== fast path: CSR gather (bf16 ego copy) -> LDS -> GEMM ========
__global__ __launch_bounds__(256) void k_fused(
        const int* __restrict__ rowptr, const int* __restrict__ ccol,
        const uint16_t* __restrict__ cvalb, const uint32_t* __restrict__ egob,
        const float2* __restrict__ egf, const float2* __restrict__ hh,
        const uint16_t* __restrict__ M1T, const uint16_t* __restrict__ M2T,
        const float* __restrict__ b1, const float* __restrict__ b2,
        float* __restrict__ out, int N) {
    __shared__ __attribute__((aligned(16))) uint16_t sT1[16 * TSTR];
    __shared__ __attribute__((aligned(16))) uint16_t sT2[16 * TSTR];
    int tid = threadIdx.x;
    int wave = tid >> 6, lane = tid & 63;
    int base = blockIdx.x * 16;
    uint32_t* s1d = (uint32_t*)sT1;
    uint32_t* s2d = (uint32_t*)sT2;

#pragma unroll
    for (int i = 0; i < 4; i++) {
        int node = base + wave * 4 + i;
        float t1x = 0.f, t1y = 0.f, t2x = 0.f, t2y = 0.f;
        if (node < N) {
            int e0 = rowptr[node], e1 = rowptr[node + 1];
            float ax = 0.f, ay = 0.f;
            for (int e = e0; e < e1; e++) {
                int c0 = ccol[e];
                c0 = min(max(c0, 0), N - 1);
                float v0 = bf2f(cvalb[e]);
                uint32_t u0 = egob[c0 * 64 + lane];
                ax += v0 * lo_f(u0);
                ay += v0 * hi_f(u0);
            }
            float2 se = egf[node * 64 + lane];
            float2 sh = hh[node * 64 + lane];
            t1x = 0.9f * (se.x + ax) + 0.1f * sh.x;
            t1y = 0.9f * (se.y + ay) + 0.1f * sh.y;
            t2x = 0.9f * (se.x * ax) + 0.1f * sh.x;
            t2y = 0.9f * (se.y * ay) + 0.1f * sh.y;
        }
        int r = wave * 4 + i;
        s1d[r * (TSTR / 2) + lane] = pack2(t1x, t1y);
        s2d[r * (TSTR / 2) + lane] = pack2(t2x, t2y);
    }
    __syncthreads();
    gemm_phase(sT1, sT2, M1T, M2T, b1, b2, out, base, wave, lane, N);
}

// ======== fallback path (tiny ws): f32 side accumulated in-place in d_out ====
__global__ __launch_bounds__(256) void k_coo_side(
        const int* __restrict__ row, const int* __restrict__ col,
        const float* __restrict__ vals, const float2* __restrict__ egf,
        float* __restrict__ sideF, int E, int N) {
    long long t = (long long)blockIdx.x * blockDim.x + threadIdx.x;
    int e = (int)(t >> 6), l = (int)(t & 63);
    if (e >= E) return;
    int c = col[e]; c = min(max(c, 0), N - 1);
    int r = row[e]; r = min(max(r, 0), N - 1);
    float v = vals[e];
    float2 u = egf[c * 64 + l];
    atomicAdd(&sideF[r * D + 2 * l],     v * u.x);
    atomicAdd(&sideF[r * D + 2 * l + 1], v * u.y);
}

__global__ __launch_bounds__(256) void k_fused2(
        const float2* __restrict__ egf, const float2* __restrict__ hh,
        const uint16_t* __restrict__ M1T, const uint16_t* __restrict__ M2T,
        const float* __restrict__ b1, const float* __restrict__ b2,
        float* __restrict__ out, int N) {
    __shared__ __attribute__((aligned(16))) uint16_t sT1[16 * TSTR];
    __shared__ __attribute__((aligned(16))) uint16_t sT2[16 * TSTR];
    int tid = threadIdx.x;
    int wave = tid >> 6, lane = tid & 63;
    int base = blockIdx.x * 16;
    const float2* sd = (const float2*)out;   // f32 side lives in d_out
    uint32_t* s1d = (uint32_t*)sT1;
    uint32_t* s2d = (uint32_t*)sT2;

#pragma unroll
    for (int i = 0; i < 4; i++) {
        int node = base + wave * 4 + i;
        float t1x = 0.f, t1y = 0.f, t2x = 0.f, t2y = 0.f;
        if (node < N) {
            float2 us = sd[node * 64 + lane];   // this block's own rows only
            float2 se = egf[node * 64 + lane];
            float2 sh = hh[node * 64 + lane];
            t1x = 0.9f * (se.x + us.x) + 0.1f * sh.x;
            t1y = 0.9f * (se.y + us.y) + 0.1f * sh.y;
            t2x = 0.9f * (se.x * us.x) + 0.1f * sh.x;
            t2y = 0.9f * (se.y * us.y) + 0.1f * sh.y;
        }
        int r = wave * 4 + i;
        s1d[r * (TSTR / 2) + lane] = pack2(t1x, t1y);
        s2d[r * (TSTR / 2) + lane] = pack2(t2x, t2y);
    }
    __syncthreads();   // all side reads done; safe to overwrite in place
    gemm_phase(sT1, sT2, M1T, M2T, b1, b2, out, base, wave, lane, N);
}

extern "C" void kernel_launch(void* const* d_in, const int* in_sizes, int n_in,
                              void* d_out, int out_size, void* d_ws, size_t ws_size,
                              hipStream_t stream) {
    const float* ego  = (const float*)d_in[0];
    const float* h0   = (const float*)d_in[1];
    const float* vals = (const float*)d_in[2];
    const float* W    = (const float*)d_in[3];
    const float* w1   = (const float*)d_in[4];
    const float* b1   = (const float*)d_in[5];
    const float* w2   = (const float*)d_in[6];
    const float* b2   = (const float*)d_in[7];
    const int* row = (const int*)d_in[8];
    const int* col = (const int*)d_in[9];
    int N = in_sizes[0] / D;
    int E = in_sizes[2];

    char* p = (char*)d_ws;
    auto alloc = [&](size_t bytes) -> char* {
        char* q = p;
        p += (bytes + 511) & ~(size_t)511;
        return q;
    };
    // small stuff first so the fallback needs only the head of d_ws
    uint16_t* M1T    = (uint16_t*)alloc(D * D * 2);
    uint16_t* M2T    = (uint16_t*)alloc(D * D * 2);
    uint32_t* egob   = (uint32_t*)alloc((size_t)N * 64 * 4);   // bf16-pair ego copy
    int*      deg    = (int*)alloc((size_t)N * 4);
    int*      rowptr = (int*)alloc((size_t)(N + 1) * 4);
    int*      wp     = (int*)alloc((size_t)N * 4);
    int*      bsum   = (int*)alloc(1024 * 4);
    int*      boff   = (int*)alloc(1024 * 4);
    int*      ccol   = (int*)alloc((size_t)E * 4);
    uint16_t* cvalb  = (uint16_t*)alloc((size_t)E * 2);
    size_t need_fast = (size_t)(p - (char*)d_ws);

    k_prep<<<D, D, 0, stream>>>(W, w1, w2, M1T, M2T);

    if (ws_size >= need_fast) {
        // ---- fast path: CSR + fused gather/GEMM ----
        hipMemsetAsync(deg, 0, (size_t)N * 4, stream);
        int npairs = N * 64;
        k_cvt<<<(npairs + 255) / 256, 256, 0, stream>>>((const float2*)ego, egob, npairs);
        int nb = (N + 1023) / 1024;
        k_hist<<<(E + 255) / 256, 256, 0, stream>>>(row, deg, E, N);
        k_scan1<<<nb, 1024, 0, stream>>>(deg, rowptr, bsum, N);
        k_scan2<<<1, 1, 0, stream>>>(bsum, boff, nb, rowptr, N);
        k_scan3<<<nb, 1024, 0, stream>>>(deg, boff, rowptr, wp, N);
        k_scatter<<<(E + 255) / 256, 256, 0, stream>>>(row, col, vals, wp, ccol, cvalb, E, N);
        int nblocks = (N + 15) / 16;
        k_fused<<<nblocks, 256, 0, stream>>>(rowptr, ccol, cvalb, egob,
                                             (const float2*)ego, (const float2*)h0,
                                             M1T, M2T, b1, b2, (float*)d_out, N);
    } else {
        // ---- fallback: needs only ~128KB ws; f32 side accumulated in d_out ----
        hipMemsetAsync(d_out, 0, (size_t)out_size * 4, stream);
        long long tthr = (long long)E * 64;
        int blocks = (int)((tthr + 255) / 256);
        k_coo_side<<<blocks, 256, 0, stream>>>(row, col, vals, (const float2*)ego,
                                               (float*)d_out, E, N);
        int nblocks = (N + 15) / 16;
        k_fused2<<<nblocks, 256, 0, stream>>>((const float2*)ego, (const float2*)h0,
                                              M1T, M2T, b1, b2, (float*)d_out, N);
    }
}

// Round 6
// 760.706 us; speedup vs baseline: 1.1923x; 1.1923x over previous
//
#include <hip/hip_runtime.h>
#include <stdint.h>

#define D 128
#define BETA 0.40546510810816444f   // log(1.5)
#define TSTR 136                     // padded LDS row stride (bf16 elems)

typedef __bf16 bf16x8 __attribute__((ext_vector_type(8)));
typedef float f32x4 __attribute__((ext_vector_type(4)));

__device__ __forceinline__ float bf2f(uint16_t u) {
    union { uint32_t i; float f; } x; x.i = ((uint32_t)u) << 16; return x.f;
}
__device__ __forceinline__ uint16_t f2bf(float f) {
    union { float f; uint32_t i; } x; x.f = f;
    uint32_t r = (x.i + 0x7fffu + ((x.i >> 16) & 1u)) >> 16;
    return (uint16_t)r;
}
__device__ __forceinline__ float lo_f(uint32_t u) { return __uint_as_float(u << 16); }
__device__ __forceinline__ float hi_f(uint32_t u) { return __uint_as_float(u & 0xffff0000u); }
__device__ __forceinline__ uint32_t pack2(float x, float y) {
    return (uint32_t)f2bf(x) | ((uint32_t)f2bf(y) << 16);
}

// ================= CSR build =================
__global__ void k_hist(const int* __restrict__ row, int* __restrict__ deg, int E, int N) {
    int e = blockIdx.x * blockDim.x + threadIdx.x;
    if (e < E) {
        int r = row[e]; r = min(max(r, 0), N - 1);
        atomicAdd(&deg[r], 1);
    }
}

__global__ void k_scan1(const int* __restrict__ deg, int* __restrict__ inc,
                        int* __restrict__ bsum, int n) {
    __shared__ int s[1024];
    int i = blockIdx.x * 1024 + threadIdx.x;
    int v = (i < n) ? deg[i] : 0;
    s[threadIdx.x] = v;
    __syncthreads();
    for (int d = 1; d < 1024; d <<= 1) {
        int t = (threadIdx.x >= (unsigned)d) ? s[threadIdx.x - d] : 0;
        __syncthreads();
        s[threadIdx.x] += t;
        __syncthreads();
    }
    if (i < n) inc[i] = s[threadIdx.x];
    if (threadIdx.x == 1023) bsum[blockIdx.x] = s[1023];
}

__global__ void k_scan2(const int* __restrict__ bsum, int* __restrict__ boff,
                        int nb, int* __restrict__ rowptr, int N) {
    int run = 0;
    for (int b = 0; b < nb; b++) { boff[b] = run; run += bsum[b]; }
    rowptr[N] = run;
}

__global__ void k_scan3(const int* __restrict__ deg, const int* __restrict__ boff,
                        int* __restrict__ rowptr, int* __restrict__ wp, int n) {
    int i = blockIdx.x * 1024 + threadIdx.x;
    if (i < n) {
        int ex = rowptr[i] - deg[i] + boff[blockIdx.x];
        rowptr[i] = ex;
        wp[i] = ex;
    }
}

// single aligned 8B scattered store per edge: {col, f32 val bits}
__global__ void k_scatter(const int* __restrict__ row, const int* __restrict__ col,
                          const float* __restrict__ vals, int* __restrict__ wp,
                          uint2* __restrict__ rec, int E, int N) {
    int e = blockIdx.x * blockDim.x + threadIdx.x;
    if (e < E) {
        int r = row[e]; r = min(max(r, 0), N - 1);
        int pos = atomicAdd(&wp[r], 1);
        pos = min(max(pos, 0), E - 1);
        uint2 rv;
        rv.x = (uint32_t)col[e];
        rv.y = __float_as_uint(vals[e]);
        rec[pos] = rv;
    }
}

// ======== ego f32 -> packed bf16 dwords (halves gather traffic) ========
__global__ void k_cvt(const float4* __restrict__ src, uint2* __restrict__ dst, int n) {
    int i = blockIdx.x * blockDim.x + threadIdx.x;
    if (i < n) {
        float4 v = src[i];
        uint2 o; o.x = pack2(v.x, v.y); o.y = pack2(v.z, v.w);
        dst[i] = o;
    }
}

// ======== M1T=(IM@w1)^T, M2T=(IM@w2)^T, n-major, bf16 ========
__global__ void k_prep(const float* __restrict__ W, const float* __restrict__ w1,
                       const float* __restrict__ w2, uint16_t* __restrict__ M1T,
                       uint16_t* __restrict__ M2T) {
    int k = blockIdx.x, n = threadIdx.x;
    __shared__ float imrow[D];
    imrow[n] = (1.0f - BETA) + BETA * W[k * D + n];
    __syncthreads();
    float s1 = 0.f, s2 = 0.f;
    for (int j = 0; j < D; j++) {
        float im = imrow[j];
        s1 += im * w1[j * D + n];
        s2 += im * w2[j * D + n];
    }
    M1T[n * D + k] = f2bf(s1);
    M2T[n * D + k] = f2bf(s2);
}

// ======== shared phase-2: dual MFMA GEMM + leaky-relu epilogue (f32 out) ====
// A frag: A[m=lane&15][k=quad*8+j] (LDS, stride TSTR). B frag from n-major M*T.
// C/D: col=lane&15, row=quad*4+reg (m89-verified).
__device__ __forceinline__ void gemm_phase(
        const uint16_t* sT1, const uint16_t* sT2,
        const uint16_t* __restrict__ M1T, const uint16_t* __restrict__ M2T,
        const float* __restrict__ b1, const float* __restrict__ b2,
        float* __restrict__ out, int base, int wave, int lane, int N) {
    int l15 = lane & 15, quad = lane >> 4;
#pragma unroll
    for (int t = 0; t < 2; t++) {
        int tn = wave * 2 + t;
        f32x4 acc1 = {0.f, 0.f, 0.f, 0.f}, acc2 = {0.f, 0.f, 0.f, 0.f};
#pragma unroll
        for (int kb = 0; kb < 4; kb++) {
            int ko = kb * 32 + quad * 8;
            bf16x8 a1 = *(const bf16x8*)(sT1 + l15 * TSTR + ko);
            bf16x8 a2 = *(const bf16x8*)(sT2 + l15 * TSTR + ko);
            bf16x8 bb1 = *(const bf16x8*)(M1T + (tn * 16 + l15) * D + ko);
            bf16x8 bb2 = *(const bf16x8*)(M2T + (tn * 16 + l15) * D + ko);
            acc1 = __builtin_amdgcn_mfma_f32_16x16x32_bf16(a1, bb1, acc1, 0, 0, 0);
            acc2 = __builtin_amdgcn_mfma_f32_16x16x32_bf16(a2, bb2, acc2, 0, 0, 0);
        }
        int colo = tn * 16 + l15;
        float bbias1 = b1[colo], bbias2 = b2[colo];
#pragma unroll
        for (int r = 0; r < 4; r++) {
            int rowi = base + quad * 4 + r;
            if (rowi < N) {
                float v1 = acc1[r] + bbias1;
                v1 = (v1 >= 0.f) ? v1 : 0.01f * v1;
                float v2 = acc2[r] + bbias2;
                v2 = (v2 >= 0.f) ? v2 : 0.01f * v2;
                out[(size_t)rowi * D + colo] = v1 + v2;   // FLOAT32 output
            }
        }
    }
}

// ======== fast path: CSR gather (bf16 ego copy) -> LDS -> GEMM ========
// Gather loop unrolled x8 with independent accumulators: 8 outstanding
// 256B ego-row loads per wave (latency-bound -> MLP). Records are
// wave-uniform loads (batch into wide s_loads).
__global__ __launch_bounds__(256) void k_fused(
        const int* __restrict__ rowptr, const uint2* __restrict__ rec,
        const uint32_t* __restrict__ egob,
        const float2* __restrict__ egf, const float2* __restrict__ hh,
        const uint16_t* __restrict__ M1T, const uint16_t* __restrict__ M2T,
        const float* __restrict__ b1, const float* __restrict__ b2,
        float* __restrict__ out, int N) {
    __shared__ __attribute__((aligned(16))) uint16_t sT1[16 * TSTR];
    __shared__ __attribute__((aligned(16))) uint16_t sT2[16 * TSTR];
    int tid = threadIdx.x;
    int wave = tid >> 6, lane = tid & 63;
    int base = blockIdx.x * 16;
    uint32_t* s1d = (uint32_t*)sT1;
    uint32_t* s2d = (uint32_t*)sT2;

#pragma unroll
    for (int i = 0; i < 4; i++) {
        int node = base + wave * 4 + i;
        float t1x = 0.f, t1y = 0.f, t2x = 0.f, t2y = 0.f;
        if (node < N) {
            int e0 = rowptr[node], e1 = rowptr[node + 1];
            float ax = 0.f, ay = 0.f, bx = 0.f, by = 0.f;
            int e = e0;
            for (; e + 8 <= e1; e += 8) {
                uint2 r0 = rec[e + 0], r1 = rec[e + 1], r2 = rec[e + 2], r3 = rec[e + 3];
                uint2 r4 = rec[e + 4], r5 = rec[e + 5], r6 = rec[e + 6], r7 = rec[e + 7];
                int c0 = min(max((int)r0.x, 0), N - 1);
                int c1 = min(max((int)r1.x, 0), N - 1);
                int c2 = min(max((int)r2.x, 0), N - 1);
                int c3 = min(max((int)r3.x, 0), N - 1);
                int c4 = min(max((int)r4.x, 0), N - 1);
                int c5 = min(max((int)r5.x, 0), N - 1);
                int c6 = min(max((int)r6.x, 0), N - 1);
                int c7 = min(max((int)r7.x, 0), N - 1);
                uint32_t u0 = egob[c0 * 64 + lane];
                uint32_t u1 = egob[c1 * 64 + lane];
                uint32_t u2 = egob[c2 * 64 + lane];
                uint32_t u3 = egob[c3 * 64 + lane];
                uint32_t u4 = egob[c4 * 64 + lane];
                uint32_t u5 = egob[c5 * 64 + lane];
                uint32_t u6 = egob[c6 * 64 + lane];
                uint32_t u7 = egob[c7 * 64 + lane];
                float v0 = __uint_as_float(r0.y), v1 = __uint_as_float(r1.y);
                float v2 = __uint_as_float(r2.y), v3 = __uint_as_float(r3.y);
                float v4 = __uint_as_float(r4.y), v5 = __uint_as_float(r5.y);
                float v6 = __uint_as_float(r6.y), v7 = __uint_as_float(r7.y);
                ax += v0 * lo_f(u0); ay += v0 * hi_f(u0);
                bx += v1 * lo_f(u1); by += v1 * hi_f(u1);
                ax += v2 * lo_f(u2); ay += v2 * hi_f(u2);
                bx += v3 * lo_f(u3); by += v3 * hi_f(u3);
                ax += v4 * lo_f(u4); ay += v4 * hi_f(u4);
                bx += v5 * lo_f(u5); by += v5 * hi_f(u5);
                ax += v6 * lo_f(u6); ay += v6 * hi_f(u6);
                bx += v7 * lo_f(u7); by += v7 * hi_f(u7);
            }
            for (; e < e1; e++) {
                uint2 rv = rec[e];
                int c = min(max((int)rv.x, 0), N - 1);
                float v = __uint_as_float(rv.y);
                uint32_t u = egob[c * 64 + lane];
                ax += v * lo_f(u); ay += v * hi_f(u);
            }
            ax += bx; ay += by;
            float2 se = egf[node * 64 + lane];
            float2 sh = hh[node * 64 + lane];
            t1x = 0.9f * (se.x + ax) + 0.1f * sh.x;
            t1y = 0.9f * (se.y + ay) + 0.1f * sh.y;
            t2x = 0.9f * (se.x * ax) + 0.1f * sh.x;
            t2y = 0.9f * (se.y * ay) + 0.1f * sh.y;
        }
        int r = wave * 4 + i;
        s1d[r * (TSTR / 2) + lane] = pack2(t1x, t1y);
        s2d[r * (TSTR / 2) + lane] = pack2(t2x, t2y);
    }
    __syncthreads();
    gemm_phase(sT1, sT2, M1T, M2T, b1, b2, out, base, wave, lane, N);
}

// ======== fallback path (tiny ws): f32 side accumulated in-place in d_out ====
__global__ __launch_bounds__(256) void k_coo_side(
        const int* __restrict__ row, const int* __restrict__ col,
        const float* __restrict__ vals, const float2* __restrict__ egf,
        float* __restrict__ sideF, int E, int N) {
    long long t = (long long)blockIdx.x * blockDim.x + threadIdx.x;
    int e = (int)(t >> 6), l = (int)(t & 63);
    if (e >= E) return;
    int c = col[e]; c = min(max(c, 0), N - 1);
    int r = row[e]; r = min(max(r, 0), N - 1);
    float v = vals[e];
    float2 u = egf[c * 64 + l];
    atomicAdd(&sideF[r * D + 2 * l],     v * u.x);
    atomicAdd(&sideF[r * D + 2 * l + 1], v * u.y);
}

__global__ __launch_bounds__(256) void k_fused2(
        const float2* __restrict__ egf, const float2* __restrict__ hh,
        const uint16_t* __restrict__ M1T, const uint16_t* __restrict__ M2T,
        const float* __restrict__ b1, const float* __restrict__ b2,
        float* __restrict__ out, int N) {
    __shared__ __attribute__((aligned(16))) uint16_t sT1[16 * TSTR];
    __shared__ __attribute__((aligned(16))) uint16_t sT2[16 * TSTR];
    int tid = threadIdx.x;
    int wave = tid >> 6, lane = tid & 63;
    int base = blockIdx.x * 16;
    const float2* sd = (const float2*)out;   // f32 side lives in d_out
    uint32_t* s1d = (uint32_t*)sT1;
    uint32_t* s2d = (uint32_t*)sT2;

#pragma unroll
    for (int i = 0; i < 4; i++) {
        int node = base + wave * 4 + i;
        float t1x = 0.f, t1y = 0.f, t2x = 0.f, t2y = 0.f;
        if (node < N) {
            float2 us = sd[node * 64 + lane];   // this block's own rows only
            float2 se = egf[node * 64 + lane];
            float2 sh = hh[node * 64 + lane];
            t1x = 0.9f * (se.x + us.x) + 0.1f * sh.x;
            t1y = 0.9f * (se.y + us.y) + 0.1f * sh.y;
            t2x = 0.9f * (se.x * us.x) + 0.1f * sh.x;
            t2y = 0.9f * (se.y * us.y) + 0.1f * sh.y;
        }
        int r = wave * 4 + i;
        s1d[r * (TSTR / 2) + lane] = pack2(t1x, t1y);
        s2d[r * (TSTR / 2) + lane] = pack2(t2x, t2y);
    }
    __syncthreads();   // all side reads done; safe to overwrite in place
    gemm_phase(sT1, sT2, M1T, M2T, b1, b2, out, base, wave, lane, N);
}

extern "C" void kernel_launch(void* const* d_in, const int* in_sizes, int n_in,
                              void* d_out, int out_size, void* d_ws, size_t ws_size,
                              hipStream_t stream) {
    const float* ego  = (const float*)d_in[0];
    const float* h0   = (const float*)d_in[1];
    const float* vals = (const float*)d_in[2];
    const float* W    = (const float*)d_in[3];
    const float* w1   = (const float*)d_in[4];
    const float* b1   = (const float*)d_in[5];
    const float* w2   = (const float*)d_in[6];
    const float* b2   = (const float*)d_in[7];
    const int* row = (const int*)d_in[8];
    const int* col = (const int*)d_in[9];
    int N = in_sizes[0] / D;
    int E = in_sizes[2];

    char* p = (char*)d_ws;
    auto alloc = [&](size_t bytes) -> char* {
        char* q = p;
        p += (bytes + 511) & ~(size_t)511;
        return q;
    };
    uint16_t* M1T    = (uint16_t*)alloc(D * D * 2);
    uint16_t* M2T    = (uint16_t*)alloc(D * D * 2);
    uint32_t* egob   = (uint32_t*)alloc((size_t)N * 64 * 4);   // bf16-pair ego copy
    int*      deg    = (int*)alloc((size_t)N * 4);
    int*      rowptr = (int*)alloc((size_t)(N + 1) * 4);
    int*      wp     = (int*)alloc((size_t)N * 4);
    int*      bsum   = (int*)alloc(1024 * 4);
    int*      boff   = (int*)alloc(1024 * 4);
    uint2*    rec    = (uint2*)alloc((size_t)E * 8);           // {col, f32 val}
    size_t need_fast = (size_t)(p - (char*)d_ws);

    k_prep<<<D, D, 0, stream>>>(W, w1, w2, M1T, M2T);

    if (ws_size >= need_fast) {
        // ---- fast path: CSR + fused gather/GEMM ----
        hipMemsetAsync(deg, 0, (size_t)N * 4, stream);
        int nquads = N * 32;
        k_cvt<<<(nquads + 255) / 256, 256, 0, stream>>>((const float4*)ego,
                                                        (uint2*)egob, nquads);
        int nb = (N + 1023) / 1024;
        k_hist<<<(E + 255) / 256, 256, 0, stream>>>(row, deg, E, N);
        k_scan1<<<nb, 1024, 0, stream>>>(deg, rowptr, bsum, N);
        k_scan2<<<1, 1, 0, stream>>>(bsum, boff, nb, rowptr, N);
        k_scan3<<<nb, 1024, 0, stream>>>(deg, boff, rowptr, wp, N);
        k_scatter<<<(E + 255) / 256, 256, 0, stream>>>(row, col, vals, wp, rec, E, N);
        int nblocks = (N + 15) / 16;
        k_fused<<<nblocks, 256, 0, stream>>>(rowptr, rec, egob,
                                             (const float2*)ego, (const float2*)h0,
                                             M1T, M2T, b1, b2, (float*)d_out, N);
    } else {
        // ---- fallback: needs only ~128KB ws; f32 side accumulated in d_out ----
        hipMemsetAsync(d_out, 0, (size_t)out_size * 4, stream);
        long long tthr = (long long)E * 64;
        int blocks = (int)((tthr + 255) / 256);
        k_coo_side<<<blocks, 256, 0, stream>>>(row, col, vals, (const float2*)ego,
                                               (float*)d_out, E, N);
        int nblocks = (N + 15) / 16;
        k_fused2<<<nblocks, 256, 0, stream>>>((const float2*)ego, (const float2*)h0,
                                              M1T, M2T, b1, b2, (float*)d_out, N);
    }
}